// Round 2
// baseline (394.561 us; speedup 1.0000x reference)
//
#include <hip/hip_runtime.h>
#include <hip/hip_bf16.h>
#include <stdint.h>

#define B_   4
#define C_   256
#define CQK_ 32
#define N_   4096
#define NW   2                 // waves per attn block (TQ = NW*16)

typedef float f32x4  __attribute__((ext_vector_type(4)));
typedef short bf16x8 __attribute__((ext_vector_type(8)));

__device__ __forceinline__ unsigned short f2bf(float f) {
    unsigned u = __builtin_bit_cast(unsigned, f);
    u += 0x7FFFu + ((u >> 16) & 1u);   // RNE
    return (unsigned short)(u >> 16);
}

// ---------------- q/k projection: q[b][n][d] = Wq[d][:]·x[b][:][n] + bq ----------------
__global__ __launch_bounds__(256) void qk_proj(
        const float* __restrict__ x, const float* __restrict__ y,
        const float* __restrict__ Wq, const float* __restrict__ bq,
        const float* __restrict__ Wk, const float* __restrict__ bk,
        unsigned short* __restrict__ qf, unsigned short* __restrict__ kf) {
    const int n = blockIdx.x * 256 + threadIdx.x;
    const int b = blockIdx.y;
    float aq[CQK_], ak[CQK_];
#pragma unroll
    for (int d = 0; d < CQK_; ++d) { aq[d] = bq[d]; ak[d] = bk[d]; }
    const float* xp = x + (size_t)b * C_ * N_ + n;
    const float* yp = y + (size_t)b * C_ * N_ + n;
    for (int c = 0; c < C_; ++c) {
        float xv = xp[(size_t)c * N_];
        float yv = yp[(size_t)c * N_];
#pragma unroll
        for (int d = 0; d < CQK_; ++d) {
            aq[d] = fmaf(Wq[d * C_ + c], xv, aq[d]);
            ak[d] = fmaf(Wk[d * C_ + c], yv, ak[d]);
        }
    }
    unsigned* qo = (unsigned*)(qf + ((size_t)b * N_ + n) * CQK_);
    unsigned* ko = (unsigned*)(kf + ((size_t)b * N_ + n) * CQK_);
#pragma unroll
    for (int i = 0; i < CQK_ / 2; ++i) {
        qo[i] = (unsigned)f2bf(aq[2 * i]) | ((unsigned)f2bf(aq[2 * i + 1]) << 16);
        ko[i] = (unsigned)f2bf(ak[2 * i]) | ((unsigned)f2bf(ak[2 * i + 1]) << 16);
    }
}

// ---------------- v projection, stored TRANSPOSED: vT[b][e][m] ----------------
__global__ __launch_bounds__(256) void v_proj(
        const float* __restrict__ y, const float* __restrict__ Wv,
        const float* __restrict__ bv, unsigned short* __restrict__ vT) {
    const int m  = blockIdx.x * 256 + threadIdx.x;
    const int b  = blockIdx.z;
    const int e0 = blockIdx.y * 32;
    float acc[32];
#pragma unroll
    for (int j = 0; j < 32; ++j) acc[j] = bv[e0 + j];
    const float* yp = y + (size_t)b * C_ * N_ + m;
    for (int c = 0; c < C_; ++c) {
        float yv = yp[(size_t)c * N_];
#pragma unroll
        for (int j = 0; j < 32; ++j)
            acc[j] = fmaf(Wv[(e0 + j) * C_ + c], yv, acc[j]);
    }
#pragma unroll
    for (int j = 0; j < 32; ++j)
        vT[((size_t)b * C_ + e0 + j) * N_ + m] = f2bf(acc[j]);
}

// ---------------- fused flash attention + epilogue ----------------
// block: NW waves, each wave owns 16 query rows. TQ=NW*16, TK=64.
// LDS: V^T tile [256e][64m] bf16 (32KB, XOR-swizzled 16B slots) + per-wave P tile (2KB).
__global__ __launch_bounds__(NW * 64) void attn_kernel(
        const unsigned short* __restrict__ qf, const unsigned short* __restrict__ kf,
        const unsigned short* __restrict__ vT, const float* __restrict__ x,
        const float* __restrict__ gamma, float* __restrict__ out) {
    __shared__ char lds[32768 + NW * 2048];
    const int tid = threadIdx.x;
    const int w = tid >> 6, l = tid & 63;
    const int b  = blockIdx.y;
    const int Q0 = blockIdx.x * (NW * 16);

    // Q fragment (A of QK^T): lane holds Q[row=l%16][k=(l/16)*8 + j]
    const int qrow = Q0 + w * 16 + (l & 15);
    const bf16x8 qfrag =
        *(const bf16x8*)(qf + ((size_t)b * N_ + qrow) * CQK_ + (l >> 4) * 8);

    f32x4 acc[16];
#pragma unroll
    for (int i = 0; i < 16; ++i) acc[i] = (f32x4){0.f, 0.f, 0.f, 0.f};
    float L[4] = {0.f, 0.f, 0.f, 0.f};

    char* p_lds = lds + 32768 + w * 2048;   // per-wave P tile [16q][64m] bf16, swizzled

    for (int kt = 0; kt < N_ / 64; ++kt) {
        const int M0 = kt * 64;
        // ---- stage V^T tile: LDS linear dest, swizzle folded into GLOBAL source (T2/m173) ----
        {
            const int er = l >> 3;       // row-in-chunk 0..7
            const int s  = l & 7;        // 16B slot 0..7
#pragma unroll
            for (int i = 0; i < 32 / NW; ++i) {
                const int ci = i * NW + w;          // chunk 0..31 (wave-uniform LDS base)
                const int e  = ci * 8 + er;         // 0..255
                const unsigned short* gp =
                    vT + ((size_t)b * C_ + e) * N_ + M0 + ((s ^ (e & 7)) * 8);
                __builtin_amdgcn_global_load_lds(
                    (const __attribute__((address_space(1))) void*)gp,
                    (__attribute__((address_space(3))) void*)(lds + ci * 1024),
                    16, 0, 0);
            }
        }
        __syncthreads();

        // ---- QK^T: energy [16q][64m] for this wave, K-frags straight from global ----
        f32x4 ea[4];
#pragma unroll
        for (int mblk = 0; mblk < 4; ++mblk) {
            const bf16x8 kfrag = *(const bf16x8*)(
                kf + ((size_t)b * N_ + M0 + mblk * 16 + (l & 15)) * CQK_ + (l >> 4) * 8);
            ea[mblk] = __builtin_amdgcn_mfma_f32_16x16x32_bf16(
                qfrag, kfrag, (f32x4){0.f, 0.f, 0.f, 0.f}, 0, 0, 0);
        }

        // ---- softmax numerator (energies are O(1): no max subtraction needed) ----
#pragma unroll
        for (int mblk = 0; mblk < 4; ++mblk) {
#pragma unroll
            for (int r = 0; r < 4; ++r) {
                const float p = __expf(ea[mblk][r]);
                L[r] += p;
                const int q = (l >> 4) * 4 + r;     // D layout: row=(l>>4)*4+reg
                const int m = mblk * 16 + (l & 15); //           col=l&15
                const int byte = q * 128 + (((m >> 3) ^ (q & 7)) * 16) + (m & 7) * 2;
                *(unsigned short*)(p_lds + byte) = f2bf(p);
            }
        }

        // ---- PV: acc[q][e] += P[q][m] * V[m][e]  (A=P from LDS, B=V^T tile) ----
#pragma unroll
        for (int kblk = 0; kblk < 2; ++kblk) {
            const int qa = l & 15;
            const bf16x8 pa = *(const bf16x8*)(
                p_lds + qa * 128 + (((kblk * 4 + (l >> 4)) ^ (qa & 7)) * 16));
#pragma unroll
            for (int eblk = 0; eblk < 16; ++eblk) {
                const int e = eblk * 16 + (l & 15);
                const bf16x8 vb = *(const bf16x8*)(
                    lds + e * 128 + (((kblk * 4 + (l >> 4)) ^ (e & 7)) * 16));
                acc[eblk] = __builtin_amdgcn_mfma_f32_16x16x32_bf16(pa, vb, acc[eblk], 0, 0, 0);
            }
        }
        __syncthreads();   // protect V tile before next stage
    }

    // reduce L across the 16 lanes of each row group (xor masks <16 stay in-group)
#pragma unroll
    for (int r = 0; r < 4; ++r) {
#pragma unroll
        for (int off = 1; off < 16; off <<= 1) L[r] += __shfl_xor(L[r], off);
    }

    const float g = gamma[0];
#pragma unroll
    for (int eblk = 0; eblk < 16; ++eblk) {
        const int ch = eblk * 16 + (l & 15);
#pragma unroll
        for (int r = 0; r < 4; ++r) {
            const int n = Q0 + w * 16 + (l >> 4) * 4 + r;
            const size_t idx = ((size_t)b * C_ + ch) * N_ + n;
            out[idx] = g * acc[eblk][r] / L[r] + x[idx];
        }
    }
}

extern "C" void kernel_launch(void* const* d_in, const int* in_sizes, int n_in,
                              void* d_out, int out_size, void* d_ws, size_t ws_size,
                              hipStream_t stream) {
    (void)in_sizes; (void)n_in; (void)out_size; (void)ws_size;
    const float* x     = (const float*)d_in[0];
    const float* y     = (const float*)d_in[1];
    const float* Wq    = (const float*)d_in[2];
    const float* bq    = (const float*)d_in[3];
    const float* Wk    = (const float*)d_in[4];
    const float* bk    = (const float*)d_in[5];
    const float* Wv    = (const float*)d_in[6];
    const float* bv    = (const float*)d_in[7];
    const float* gamma = (const float*)d_in[8];
    float* out = (float*)d_out;

    // workspace: q (1MB) | k (1MB) | vT (8MB), all bf16
    unsigned short* qf = (unsigned short*)d_ws;
    unsigned short* kf = qf + (size_t)B_ * N_ * CQK_;
    unsigned short* vT = kf + (size_t)B_ * N_ * CQK_;

    qk_proj<<<dim3(N_ / 256, B_), 256, 0, stream>>>(x, y, Wq, bq, Wk, bk, qf, kf);
    v_proj <<<dim3(N_ / 256, 8, B_), 256, 0, stream>>>(y, Wv, bv, vT);
    attn_kernel<<<dim3(N_ / (NW * 16), B_), NW * 64, 0, stream>>>(qf, kf, vT, x, gamma, out);
}

// Round 3
// 288.291 us; speedup vs baseline: 1.3686x; 1.3686x over previous
//
#include <hip/hip_runtime.h>
#include <hip/hip_bf16.h>
#include <stdint.h>

#define B_   4
#define C_   256
#define CQK_ 32
#define N_   4096
#define NW   2                 // waves per attn block (TQ = NW*16)

typedef float f32x4  __attribute__((ext_vector_type(4)));
typedef short bf16x8 __attribute__((ext_vector_type(8)));

__device__ __forceinline__ unsigned short f2bf(float f) {
    unsigned u = __builtin_bit_cast(unsigned, f);
    u += 0x7FFFu + ((u >> 16) & 1u);   // RNE
    return (unsigned short)(u >> 16);
}

// ---------------- q/k projection, occupancy-fixed ----------------
// block = 4 waves; wave g handles 16 output channels (g0:q[0:16] g1:q[16:32]
// g2:k[0:16] g3:k[16:32]) for 64 consecutive pixels. 256 blocks total.
__global__ __launch_bounds__(256) void qk_proj(
        const float* __restrict__ x, const float* __restrict__ y,
        const float* __restrict__ Wq, const float* __restrict__ bq,
        const float* __restrict__ Wk, const float* __restrict__ bk,
        unsigned short* __restrict__ qf, unsigned short* __restrict__ kf) {
    const int l = threadIdx.x & 63;
    const int g = threadIdx.x >> 6;          // wave id 0..3 (wave-uniform)
    const int n = blockIdx.x * 64 + l;
    const int b = blockIdx.y;
    const bool isq = (g < 2);
    const float* __restrict__ src  = isq ? x  : y;
    const float* __restrict__ W    = isq ? Wq : Wk;
    const float* __restrict__ bias = isq ? bq : bk;
    const int d0 = (g & 1) * 16;

    float acc[16];
#pragma unroll
    for (int d = 0; d < 16; ++d) acc[d] = bias[d0 + d];

    const float* sp = src + (size_t)b * C_ * N_ + n;
    for (int c = 0; c < C_; ++c) {
        const float v = sp[(size_t)c * N_];
#pragma unroll
        for (int d = 0; d < 16; ++d)
            acc[d] = fmaf(W[(d0 + d) * C_ + c], v, acc[d]);
    }

    unsigned* dst = (unsigned*)((isq ? qf : kf) + ((size_t)b * N_ + n) * CQK_ + d0);
#pragma unroll
    for (int i = 0; i < 8; ++i)
        dst[i] = (unsigned)f2bf(acc[2 * i]) | ((unsigned)f2bf(acc[2 * i + 1]) << 16);
}

// ---------------- v projection, stored TRANSPOSED: vT[b][e][m] ----------------
__global__ __launch_bounds__(256) void v_proj(
        const float* __restrict__ y, const float* __restrict__ Wv,
        const float* __restrict__ bv, unsigned short* __restrict__ vT) {
    const int m  = blockIdx.x * 256 + threadIdx.x;
    const int b  = blockIdx.z;
    const int e0 = blockIdx.y * 32;
    float acc[32];
#pragma unroll
    for (int j = 0; j < 32; ++j) acc[j] = bv[e0 + j];
    const float* yp = y + (size_t)b * C_ * N_ + m;
    for (int c = 0; c < C_; ++c) {
        float yv = yp[(size_t)c * N_];
#pragma unroll
        for (int j = 0; j < 32; ++j)
            acc[j] = fmaf(Wv[(e0 + j) * C_ + c], yv, acc[j]);
    }
#pragma unroll
    for (int j = 0; j < 32; ++j)
        vT[((size_t)b * C_ + e0 + j) * N_ + m] = f2bf(acc[j]);
}

// ---------------- fused flash attention + epilogue ----------------
// block: NW waves, each wave owns 16 query rows. TQ=NW*16, TK=64.
// LDS: V^T tile [256e][64m] bf16 (32KB, XOR-swizzled 16B slots) + per-wave P tile (2KB).
__global__ __launch_bounds__(NW * 64) void attn_kernel(
        const unsigned short* __restrict__ qf, const unsigned short* __restrict__ kf,
        const unsigned short* __restrict__ vT, const float* __restrict__ x,
        const float* __restrict__ gamma, float* __restrict__ out) {
    __shared__ char lds[32768 + NW * 2048];
    const int tid = threadIdx.x;
    const int w = tid >> 6, l = tid & 63;
    const int b  = blockIdx.y;
    const int Q0 = blockIdx.x * (NW * 16);

    // Q fragment (A of QK^T): lane holds Q[row=l%16][k=(l/16)*8 + j]
    const int qrow = Q0 + w * 16 + (l & 15);
    const bf16x8 qfrag =
        *(const bf16x8*)(qf + ((size_t)b * N_ + qrow) * CQK_ + (l >> 4) * 8);

    f32x4 acc[16];
#pragma unroll
    for (int i = 0; i < 16; ++i) acc[i] = (f32x4){0.f, 0.f, 0.f, 0.f};
    float L[4] = {0.f, 0.f, 0.f, 0.f};

    char* p_lds = lds + 32768 + w * 2048;   // per-wave P tile [16q][64m] bf16, swizzled

    for (int kt = 0; kt < N_ / 64; ++kt) {
        const int M0 = kt * 64;
        // ---- stage V^T tile: LDS linear dest, swizzle folded into GLOBAL source (T2/m173) ----
        {
            const int er = l >> 3;       // row-in-chunk 0..7
            const int s  = l & 7;        // 16B slot 0..7
#pragma unroll
            for (int i = 0; i < 32 / NW; ++i) {
                const int ci = i * NW + w;          // chunk 0..31 (wave-uniform LDS base)
                const int e  = ci * 8 + er;         // 0..255
                const unsigned short* gp =
                    vT + ((size_t)b * C_ + e) * N_ + M0 + ((s ^ (e & 7)) * 8);
                __builtin_amdgcn_global_load_lds(
                    (const __attribute__((address_space(1))) void*)gp,
                    (__attribute__((address_space(3))) void*)(lds + ci * 1024),
                    16, 0, 0);
            }
        }
        __syncthreads();

        // ---- QK^T: energy [16q][64m] for this wave, K-frags straight from global ----
        f32x4 ea[4];
#pragma unroll
        for (int mblk = 0; mblk < 4; ++mblk) {
            const bf16x8 kfrag = *(const bf16x8*)(
                kf + ((size_t)b * N_ + M0 + mblk * 16 + (l & 15)) * CQK_ + (l >> 4) * 8);
            ea[mblk] = __builtin_amdgcn_mfma_f32_16x16x32_bf16(
                qfrag, kfrag, (f32x4){0.f, 0.f, 0.f, 0.f}, 0, 0, 0);
        }

        // ---- softmax numerator (energies are O(1): no max subtraction needed) ----
#pragma unroll
        for (int mblk = 0; mblk < 4; ++mblk) {
#pragma unroll
            for (int r = 0; r < 4; ++r) {
                const float p = __expf(ea[mblk][r]);
                L[r] += p;
                const int q = (l >> 4) * 4 + r;     // D layout: row=(l>>4)*4+reg
                const int m = mblk * 16 + (l & 15); //           col=l&15
                const int byte = q * 128 + (((m >> 3) ^ (q & 7)) * 16) + (m & 7) * 2;
                *(unsigned short*)(p_lds + byte) = f2bf(p);
            }
        }

        // ---- PV: acc[q][e] += P[q][m] * V[m][e]  (A=P from LDS, B=V^T tile) ----
#pragma unroll
        for (int kblk = 0; kblk < 2; ++kblk) {
            const int qa = l & 15;
            const bf16x8 pa = *(const bf16x8*)(
                p_lds + qa * 128 + (((kblk * 4 + (l >> 4)) ^ (qa & 7)) * 16));
#pragma unroll
            for (int eblk = 0; eblk < 16; ++eblk) {
                const int e = eblk * 16 + (l & 15);
                const bf16x8 vb = *(const bf16x8*)(
                    lds + e * 128 + (((kblk * 4 + (l >> 4)) ^ (e & 7)) * 16));
                acc[eblk] = __builtin_amdgcn_mfma_f32_16x16x32_bf16(pa, vb, acc[eblk], 0, 0, 0);
            }
        }
        __syncthreads();   // protect V tile before next stage
    }

    // reduce L across the 16 lanes of each row group (xor masks <16 stay in-group)
#pragma unroll
    for (int r = 0; r < 4; ++r) {
#pragma unroll
        for (int off = 1; off < 16; off <<= 1) L[r] += __shfl_xor(L[r], off);
    }

    const float g = gamma[0];
#pragma unroll
    for (int eblk = 0; eblk < 16; ++eblk) {
        const int ch = eblk * 16 + (l & 15);
#pragma unroll
        for (int r = 0; r < 4; ++r) {
            const int n = Q0 + w * 16 + (l >> 4) * 4 + r;
            const size_t idx = ((size_t)b * C_ + ch) * N_ + n;
            out[idx] = g * acc[eblk][r] / L[r] + x[idx];
        }
    }
}

extern "C" void kernel_launch(void* const* d_in, const int* in_sizes, int n_in,
                              void* d_out, int out_size, void* d_ws, size_t ws_size,
                              hipStream_t stream) {
    (void)in_sizes; (void)n_in; (void)out_size; (void)ws_size;
    const float* x     = (const float*)d_in[0];
    const float* y     = (const float*)d_in[1];
    const float* Wq    = (const float*)d_in[2];
    const float* bq    = (const float*)d_in[3];
    const float* Wk    = (const float*)d_in[4];
    const float* bk    = (const float*)d_in[5];
    const float* Wv    = (const float*)d_in[6];
    const float* bv    = (const float*)d_in[7];
    const float* gamma = (const float*)d_in[8];
    float* out = (float*)d_out;

    // workspace: q (1MB) | k (1MB) | vT (8MB), all bf16
    unsigned short* qf = (unsigned short*)d_ws;
    unsigned short* kf = qf + (size_t)B_ * N_ * CQK_;
    unsigned short* vT = kf + (size_t)B_ * N_ * CQK_;

    qk_proj<<<dim3(N_ / 64, B_), 256, 0, stream>>>(x, y, Wq, bq, Wk, bk, qf, kf);
    v_proj <<<dim3(N_ / 256, 8, B_), 256, 0, stream>>>(y, Wv, bv, vT);
    attn_kernel<<<dim3(N_ / (NW * 16), B_), NW * 64, 0, stream>>>(qf, kf, vT, x, gamma, out);
}

// Round 4
// 262.264 us; speedup vs baseline: 1.5044x; 1.0992x over previous
//
#include <hip/hip_runtime.h>
#include <hip/hip_bf16.h>
#include <stdint.h>

#define B_   4
#define C_   256
#define CQK_ 32
#define N_   4096

typedef float f32x4  __attribute__((ext_vector_type(4)));
typedef short bf16x8 __attribute__((ext_vector_type(8)));

__device__ __forceinline__ unsigned short f2bf(float f) {
    unsigned u = __builtin_bit_cast(unsigned, f);
    u += 0x7FFFu + ((u >> 16) & 1u);   // RNE
    return (unsigned short)(u >> 16);
}

// V stored pre-fragmented for PV MFMA B-operands:
// element (b, e, m) lives at [b][m>>6][(m>>5)&1][e>>4][((m>>3)&3)*16 + (e&15)][m&7]
// so a B-fragment load (fixed tile/ks/eblk) is lane-linear: elem = base + l*8 + j.
__device__ __forceinline__ size_t vfrag_off(int b, int e, int m) {
    return ((((((size_t)b * 64 + (m >> 6)) * 2 + ((m >> 5) & 1)) * 16 + (e >> 4)) * 64)
            + (size_t)((m >> 3) & 3) * 16 + (e & 15)) * 8 + (m & 7);
}

// ---------------- fused projections: blocks 0..511 = V, 512..767 = Q/K ----------------
__global__ __launch_bounds__(256) void proj_kernel(
        const float* __restrict__ x, const float* __restrict__ y,
        const float* __restrict__ Wq, const float* __restrict__ bq,
        const float* __restrict__ Wk, const float* __restrict__ bk,
        const float* __restrict__ Wv, const float* __restrict__ bv,
        unsigned short* __restrict__ qf, unsigned short* __restrict__ kf,
        unsigned short* __restrict__ vf) {
    const int bid = blockIdx.x;
    const int tid = threadIdx.x;
    if (bid < 512) {
        // ---- V projection into fragment layout ----
        // bid bits: [0:4]=m-tile(32) [5:6]=e-grp(4) [7:8]=batch(4); thread: px=tid&127, eh=tid>>7
        const int m  = (bid & 31) * 128 + (tid & 127);
        const int e0 = ((bid >> 5) & 3) * 64 + (tid >> 7) * 32;
        const int b  = bid >> 7;
        float acc[32];
#pragma unroll
        for (int j = 0; j < 32; ++j) acc[j] = bv[e0 + j];
        const float* yp = y + (size_t)b * C_ * N_ + m;
        for (int c = 0; c < C_; ++c) {
            const float yv = yp[(size_t)c * N_];
#pragma unroll
            for (int j = 0; j < 32; ++j)
                acc[j] = fmaf(Wv[(e0 + j) * C_ + c], yv, acc[j]);
        }
#pragma unroll
        for (int j = 0; j < 32; ++j)
            vf[vfrag_off(b, e0 + j, m)] = f2bf(acc[j]);
    } else {
        // ---- Q/K projection: wave g: 0=q[0:16] 1=q[16:32] 2=k[0:16] 3=k[16:32] ----
        const int j2 = bid - 512;
        const int l  = tid & 63;
        const int g  = tid >> 6;
        const int n  = (j2 & 63) * 64 + l;
        const int b  = j2 >> 6;
        const bool isq = (g < 2);
        const float* __restrict__ src  = isq ? x  : y;
        const float* __restrict__ W    = isq ? Wq : Wk;
        const float* __restrict__ bias = isq ? bq : bk;
        const int d0 = (g & 1) * 16;
        float acc[16];
#pragma unroll
        for (int d = 0; d < 16; ++d) acc[d] = bias[d0 + d];
        const float* sp = src + (size_t)b * C_ * N_ + n;
        for (int c = 0; c < C_; ++c) {
            const float v = sp[(size_t)c * N_];
#pragma unroll
            for (int d = 0; d < 16; ++d)
                acc[d] = fmaf(W[(d0 + d) * C_ + c], v, acc[d]);
        }
        unsigned* dst = (unsigned*)((isq ? qf : kf) + ((size_t)b * N_ + n) * CQK_ + d0);
#pragma unroll
        for (int i = 0; i < 8; ++i)
            dst[i] = (unsigned)f2bf(acc[2 * i]) | ((unsigned)f2bf(acc[2 * i + 1]) << 16);
    }
}

// ---------------- fused flash attention + epilogue ----------------
// 4 waves, TQ=32. QK roles: qb=w&1 (16 q-rows), mh=w>>1 (32 of 64 m).
// PV: e-split, wave owns e-range w*64 for ALL 32 q. P via double-buffered swizzled LDS.
__global__ __launch_bounds__(256) void attn_kernel(
        const unsigned short* __restrict__ qf, const unsigned short* __restrict__ kf,
        const unsigned short* __restrict__ vf, const float* __restrict__ x,
        const float* __restrict__ gamma, float* __restrict__ out) {
    __shared__ char plds[2 * 4096 + 256];
    const int tid = threadIdx.x;
    const int w = tid >> 6, l = tid & 63;
    // XCD decode: batch b -> XCDs {2b,2b+1} so K/V/Q stay L2-resident per XCD
    const int gid = blockIdx.x;
    const int b   = (gid >> 1) & 3;
    const int q0  = (((gid >> 3) << 1) | (gid & 1)) * 32;
    const int qb = w & 1, mh = w >> 1;

    const bf16x8 qfrag = *(const bf16x8*)(
        qf + ((size_t)b * N_ + q0 + qb * 16 + (l & 15)) * CQK_ + (l >> 4) * 8);

    f32x4 acc[2][4];
#pragma unroll
    for (int i = 0; i < 2; ++i)
#pragma unroll
        for (int j = 0; j < 4; ++j) acc[i][j] = (f32x4){0.f, 0.f, 0.f, 0.f};
    float L[4] = {0.f, 0.f, 0.f, 0.f};

    for (int kt = 0; kt < N_ / 64; ++kt) {
        const int M0 = kt * 64;
        char* pw = plds + ((kt & 1) << 12);

        // early-issue all global loads for this tile (coalesced 16B/lane)
        bf16x8 kfa[2];
#pragma unroll
        for (int i = 0; i < 2; ++i)
            kfa[i] = *(const bf16x8*)(
                kf + ((size_t)b * N_ + M0 + (mh * 2 + i) * 16 + (l & 15)) * CQK_ + (l >> 4) * 8);
        bf16x8 vb[8];
#pragma unroll
        for (int ks = 0; ks < 2; ++ks)
#pragma unroll
            for (int eb = 0; eb < 4; ++eb)
                vb[ks * 4 + eb] = *(const bf16x8*)(
                    vf + ((((size_t)b * 64 + kt) * 2 + ks) * 16 + (w * 4 + eb)) * 512 + l * 8);

        // QK^T for this wave's (q-half, m-half)
        f32x4 ea[2];
#pragma unroll
        for (int i = 0; i < 2; ++i)
            ea[i] = __builtin_amdgcn_mfma_f32_16x16x32_bf16(
                qfrag, kfa[i], (f32x4){0.f, 0.f, 0.f, 0.f}, 0, 0, 0);

        // softmax numerator (|energy| is O(1): no max subtraction), write P swizzled
#pragma unroll
        for (int i = 0; i < 2; ++i) {
            const int mcol = (mh * 2 + i) * 16 + (l & 15);
#pragma unroll
            for (int r = 0; r < 4; ++r) {
                const float p = __expf(ea[i][r]);
                L[r] += p;
                const int q = qb * 16 + (l >> 4) * 4 + r;
                const int byte = q * 128 + (((mcol >> 3) ^ (q & 7)) << 4) + (mcol & 7) * 2;
                *(unsigned short*)(pw + byte) = f2bf(p);
            }
        }
        __syncthreads();   // single barrier per tile (P dbuf handles WAR)

        // PV: wave's 64 e-channels for all 32 q
#pragma unroll
        for (int ks = 0; ks < 2; ++ks)
#pragma unroll
            for (int qblk = 0; qblk < 2; ++qblk) {
                const int q = qblk * 16 + (l & 15);
                const bf16x8 pa = *(const bf16x8*)(
                    pw + q * 128 + (((ks * 4 + (l >> 4)) ^ (q & 7)) << 4));
#pragma unroll
                for (int eb = 0; eb < 4; ++eb)
                    acc[qblk][eb] = __builtin_amdgcn_mfma_f32_16x16x32_bf16(
                        pa, vb[ks * 4 + eb], acc[qblk][eb], 0, 0, 0);
            }
    }

    // row-sum L within wave (16-lane groups share a q-row)
#pragma unroll
    for (int r = 0; r < 4; ++r)
#pragma unroll
        for (int off = 1; off < 16; off <<= 1) L[r] += __shfl_xor(L[r], off);

    // cross-wave combine: wave w holds rows of q-block (w&1) for m-half (w>>1)
    float* Lb = (float*)(plds + 8192);
    if ((l & 15) == 0) {
#pragma unroll
        for (int r = 0; r < 4; ++r) Lb[w * 16 + (l >> 4) * 4 + r] = L[r];
    }
    __syncthreads();

    float rL[2][4];
#pragma unroll
    for (int qblk = 0; qblk < 2; ++qblk)
#pragma unroll
        for (int r = 0; r < 4; ++r) {
            const int qi = (l >> 4) * 4 + r;
            rL[qblk][r] = 1.0f / (Lb[qblk * 16 + qi] + Lb[(qblk + 2) * 16 + qi]);
        }

    const float g = gamma[0];
#pragma unroll
    for (int qblk = 0; qblk < 2; ++qblk)
#pragma unroll
        for (int eb = 0; eb < 4; ++eb) {
            const int e = w * 64 + eb * 16 + (l & 15);
#pragma unroll
            for (int r = 0; r < 4; ++r) {
                const int n = q0 + qblk * 16 + (l >> 4) * 4 + r;
                const size_t idx = ((size_t)b * C_ + e) * N_ + n;
                out[idx] = g * acc[qblk][eb][r] * rL[qblk][r] + x[idx];
            }
        }
}

extern "C" void kernel_launch(void* const* d_in, const int* in_sizes, int n_in,
                              void* d_out, int out_size, void* d_ws, size_t ws_size,
                              hipStream_t stream) {
    (void)in_sizes; (void)n_in; (void)out_size; (void)ws_size;
    const float* x     = (const float*)d_in[0];
    const float* y     = (const float*)d_in[1];
    const float* Wq    = (const float*)d_in[2];
    const float* bq    = (const float*)d_in[3];
    const float* Wk    = (const float*)d_in[4];
    const float* bk    = (const float*)d_in[5];
    const float* Wv    = (const float*)d_in[6];
    const float* bv    = (const float*)d_in[7];
    const float* gamma = (const float*)d_in[8];
    float* out = (float*)d_out;

    // workspace: q (1MB) | k (1MB) | v-frag (8MB), all bf16
    unsigned short* qf = (unsigned short*)d_ws;
    unsigned short* kf = qf + (size_t)B_ * N_ * CQK_;
    unsigned short* vf = kf + (size_t)B_ * N_ * CQK_;

    proj_kernel<<<dim3(768), 256, 0, stream>>>(x, y, Wq, bq, Wk, bk, Wv, bv, qf, kf, vf);
    attn_kernel<<<dim3(512), 256, 0, stream>>>(qf, kf, vf, x, gamma, out);
}

// Round 5
// 93.940 us; speedup vs baseline: 4.2001x; 2.7918x over previous
//
#include <hip/hip_runtime.h>
#include <hip/hip_bf16.h>
#include <stdint.h>

#define B_   4
#define C_   256
#define CQK_ 32
#define N_   4096

typedef float f32x4  __attribute__((ext_vector_type(4)));
typedef short bf16x8 __attribute__((ext_vector_type(8)));
typedef unsigned uint4v __attribute__((ext_vector_type(4)));

__device__ __forceinline__ unsigned short f2bf(float f) {
    unsigned u = __builtin_bit_cast(unsigned, f);
    u += 0x7FFFu + ((u >> 16) & 1u);   // RNE
    return (unsigned short)(u >> 16);
}
__device__ __forceinline__ unsigned pack2(float a, float b) {
    return (unsigned)f2bf(a) | ((unsigned)f2bf(b) << 16);
}

// V fragment layout (same as round 4, consumed unchanged by attn):
// elem (b,e,m) at [b][m>>6][(m>>5)&1][e>>4][((m>>3)&3)*16+(e&15)][m&7]
__device__ __forceinline__ size_t vfrag_off(int b, int e, int m) {
    return ((((((size_t)b * 64 + (m >> 6)) * 2 + ((m >> 5) & 1)) * 16 + (e >> 4)) * 64)
            + (size_t)((m >> 3) & 3) * 16 + (e & 15)) * 8 + (m & 7);
}

// ---------------- pass 1: fp32 [b][c][n] -> bf16 [b][n][c] (+ W -> bf16) ----------------
// blocks 0..255: x -> xb_t ; 256..511: y -> yb_t ; 512..575: W conversion
__global__ __launch_bounds__(256) void transpose_kernel(
        const float* __restrict__ x, const float* __restrict__ y,
        const float* __restrict__ Wq, const float* __restrict__ Wk,
        const float* __restrict__ Wv,
        unsigned short* __restrict__ xb, unsigned short* __restrict__ yb,
        unsigned short* __restrict__ Wqb, unsigned short* __restrict__ Wkb,
        unsigned short* __restrict__ Wvb) {
    const int bid = blockIdx.x, tid = threadIdx.x;
    if (bid < 512) {
        __shared__ char lds[64 * 528];          // 64 pixel-rows x 256 bf16 (+16B pad)
        const bool isx = bid < 256;
        const int slab = bid & 255;
        const int b  = slab >> 6;
        const int n0 = (slab & 63) * 64;
        const float* __restrict__ src = isx ? x : y;
        unsigned short* __restrict__ dst = isx ? xb : yb;
        const int l = tid & 63, wv = tid >> 6;
        const float* sp = src + (size_t)(b * C_) * N_ + n0 + l;
#pragma unroll
        for (int i = 0; i < 64; i += 2) {
            const int c = wv * 64 + i;
            const float v0 = sp[(size_t)c * N_];
            const float v1 = sp[(size_t)(c + 1) * N_];
            *(unsigned*)(lds + l * 528 + c * 2) = pack2(v0, v1);
        }
        __syncthreads();
        const int n = tid >> 5, chunk = tid & 31;
#pragma unroll
        for (int j = 0; j < 8; ++j) {
            const int nn = n + j * 8;
            const uint4v v = *(const uint4v*)(lds + nn * 528 + chunk * 16);
            *(uint4v*)((char*)(dst + ((size_t)b * N_ + n0 + nn) * C_) + chunk * 16) = v;
        }
    } else {
        // W fp32 -> bf16 (pair-packed). pairs: Wq [0,4096) Wk [4096,8192) Wv [8192,40960)
        for (int p = (bid - 512) * 256 + tid; p < 40960; p += 64 * 256) {
            const float* s; unsigned short* d; int off;
            if (p < 4096)      { s = Wq; d = Wqb; off = p; }
            else if (p < 8192) { s = Wk; d = Wkb; off = p - 4096; }
            else               { s = Wv; d = Wvb; off = p - 8192; }
            *(unsigned*)(d + off * 2) = pack2(s[off * 2], s[off * 2 + 1]);
        }
    }
}

// ---------------- pass 2: MFMA projections, no LDS ----------------
// 256 blocks (b x 64 n-tiles of 64), 4 waves. Wave w: V e-range w*64 (4 eblk)
// + QK role (w0: q[0:16], w1: q[16:32], w2: k[0:16], w3: k[16:32]).
__global__ __launch_bounds__(256) void proj_gemm(
        const unsigned short* __restrict__ xb, const unsigned short* __restrict__ yb,
        const unsigned short* __restrict__ Wqb, const unsigned short* __restrict__ Wkb,
        const unsigned short* __restrict__ Wvb,
        const float* __restrict__ bq, const float* __restrict__ bk,
        const float* __restrict__ bv,
        unsigned short* __restrict__ qf, unsigned short* __restrict__ kf,
        unsigned short* __restrict__ vf) {
    const int tid = threadIdx.x, w = tid >> 6, l = tid & 63;
    const int lr = l & 15, lg = l >> 4;
    const int gid = blockIdx.x;
    const int b  = (gid >> 1) & 3;                       // batch -> XCD pair
    const int n0 = ((((gid >> 3) << 1) | (gid & 1))) * 64;

    f32x4 accV[4][4];    // [eblk][mblk]
    f32x4 accQ[4];       // [mblk]
#pragma unroll
    for (int e = 0; e < 4; ++e)
#pragma unroll
        for (int m = 0; m < 4; ++m) accV[e][m] = (f32x4){0.f, 0.f, 0.f, 0.f};
#pragma unroll
    for (int m = 0; m < 4; ++m) accQ[m] = (f32x4){0.f, 0.f, 0.f, 0.f};

    const unsigned short* __restrict__ Wqk = (w < 2) ? Wqb : Wkb;
    const int d0 = (w & 1) * 16;

#pragma unroll
    for (int ks = 0; ks < 8; ++ks) {
        const int c0 = ks * 32 + lg * 8;
        bf16x8 aY[4], aS[4];
#pragma unroll
        for (int mb = 0; mb < 4; ++mb)
            aY[mb] = *(const bf16x8*)(yb + ((size_t)b * N_ + n0 + mb * 16 + lr) * C_ + c0);
        if (w < 2) {
#pragma unroll
            for (int mb = 0; mb < 4; ++mb)
                aS[mb] = *(const bf16x8*)(xb + ((size_t)b * N_ + n0 + mb * 16 + lr) * C_ + c0);
        } else {
#pragma unroll
            for (int mb = 0; mb < 4; ++mb) aS[mb] = aY[mb];
        }
        bf16x8 bV[4];
#pragma unroll
        for (int eb = 0; eb < 4; ++eb)
            bV[eb] = *(const bf16x8*)(Wvb + (size_t)(w * 64 + eb * 16 + lr) * C_ + c0);
        const bf16x8 bQ = *(const bf16x8*)(Wqk + (size_t)(d0 + lr) * C_ + c0);
#pragma unroll
        for (int eb = 0; eb < 4; ++eb)
#pragma unroll
            for (int mb = 0; mb < 4; ++mb)
                accV[eb][mb] = __builtin_amdgcn_mfma_f32_16x16x32_bf16(
                    aY[mb], bV[eb], accV[eb][mb], 0, 0, 0);
#pragma unroll
        for (int mb = 0; mb < 4; ++mb)
            accQ[mb] = __builtin_amdgcn_mfma_f32_16x16x32_bf16(aS[mb], bQ, accQ[mb], 0, 0, 0);
    }

    // ---- V epilogue: D rows = pixels m, cols = e -> 8B contiguous stores into vf ----
#pragma unroll
    for (int eb = 0; eb < 4; ++eb) {
        const int e = w * 64 + eb * 16 + lr;
        const float bve = bv[e];
#pragma unroll
        for (int mb = 0; mb < 4; ++mb) {
            const int mbase = n0 + mb * 16 + lg * 4;
            const size_t off = vfrag_off(b, e, mbase);
            unsigned* p = (unsigned*)(vf + off);
            p[0] = pack2(accV[eb][mb][0] + bve, accV[eb][mb][1] + bve);
            p[1] = pack2(accV[eb][mb][2] + bve, accV[eb][mb][3] + bve);
        }
    }
    // ---- Q/K epilogue: [n][32] row-major, 2B scatter (small) ----
    const float bqv = ((w < 2) ? bq : bk)[d0 + lr];
    unsigned short* __restrict__ dqk = (w < 2) ? qf : kf;
#pragma unroll
    for (int mb = 0; mb < 4; ++mb)
#pragma unroll
        for (int r = 0; r < 4; ++r) {
            const int n = n0 + mb * 16 + lg * 4 + r;
            dqk[((size_t)b * N_ + n) * CQK_ + d0 + lr] = f2bf(accQ[mb][r] + bqv);
        }
}

// ---------------- fused flash attention + epilogue (unchanged from round 4) ----------------
__global__ __launch_bounds__(256) void attn_kernel(
        const unsigned short* __restrict__ qf, const unsigned short* __restrict__ kf,
        const unsigned short* __restrict__ vf, const float* __restrict__ x,
        const float* __restrict__ gamma, float* __restrict__ out) {
    __shared__ char plds[2 * 4096 + 256];
    const int tid = threadIdx.x;
    const int w = tid >> 6, l = tid & 63;
    const int gid = blockIdx.x;
    const int b   = (gid >> 1) & 3;
    const int q0  = (((gid >> 3) << 1) | (gid & 1)) * 32;
    const int qb = w & 1, mh = w >> 1;

    const bf16x8 qfrag = *(const bf16x8*)(
        qf + ((size_t)b * N_ + q0 + qb * 16 + (l & 15)) * CQK_ + (l >> 4) * 8);

    f32x4 acc[2][4];
#pragma unroll
    for (int i = 0; i < 2; ++i)
#pragma unroll
        for (int j = 0; j < 4; ++j) acc[i][j] = (f32x4){0.f, 0.f, 0.f, 0.f};
    float L[4] = {0.f, 0.f, 0.f, 0.f};

    for (int kt = 0; kt < N_ / 64; ++kt) {
        const int M0 = kt * 64;
        char* pw = plds + ((kt & 1) << 12);

        bf16x8 kfa[2];
#pragma unroll
        for (int i = 0; i < 2; ++i)
            kfa[i] = *(const bf16x8*)(
                kf + ((size_t)b * N_ + M0 + (mh * 2 + i) * 16 + (l & 15)) * CQK_ + (l >> 4) * 8);
        bf16x8 vb[8];
#pragma unroll
        for (int ks = 0; ks < 2; ++ks)
#pragma unroll
            for (int eb = 0; eb < 4; ++eb)
                vb[ks * 4 + eb] = *(const bf16x8*)(
                    vf + ((((size_t)b * 64 + kt) * 2 + ks) * 16 + (w * 4 + eb)) * 512 + l * 8);

        f32x4 ea[2];
#pragma unroll
        for (int i = 0; i < 2; ++i)
            ea[i] = __builtin_amdgcn_mfma_f32_16x16x32_bf16(
                qfrag, kfa[i], (f32x4){0.f, 0.f, 0.f, 0.f}, 0, 0, 0);

#pragma unroll
        for (int i = 0; i < 2; ++i) {
            const int mcol = (mh * 2 + i) * 16 + (l & 15);
#pragma unroll
            for (int r = 0; r < 4; ++r) {
                const float p = __expf(ea[i][r]);
                L[r] += p;
                const int q = qb * 16 + (l >> 4) * 4 + r;
                const int byte = q * 128 + (((mcol >> 3) ^ (q & 7)) << 4) + (mcol & 7) * 2;
                *(unsigned short*)(pw + byte) = f2bf(p);
            }
        }
        __syncthreads();

#pragma unroll
        for (int ks = 0; ks < 2; ++ks)
#pragma unroll
            for (int qblk = 0; qblk < 2; ++qblk) {
                const int q = qblk * 16 + (l & 15);
                const bf16x8 pa = *(const bf16x8*)(
                    pw + q * 128 + (((ks * 4 + (l >> 4)) ^ (q & 7)) << 4));
#pragma unroll
                for (int eb = 0; eb < 4; ++eb)
                    acc[qblk][eb] = __builtin_amdgcn_mfma_f32_16x16x32_bf16(
                        pa, vb[ks * 4 + eb], acc[qblk][eb], 0, 0, 0);
            }
    }

#pragma unroll
    for (int r = 0; r < 4; ++r)
#pragma unroll
        for (int off = 1; off < 16; off <<= 1) L[r] += __shfl_xor(L[r], off);

    float* Lb = (float*)(plds + 8192);
    if ((l & 15) == 0) {
#pragma unroll
        for (int r = 0; r < 4; ++r) Lb[w * 16 + (l >> 4) * 4 + r] = L[r];
    }
    __syncthreads();

    float rL[2][4];
#pragma unroll
    for (int qblk = 0; qblk < 2; ++qblk)
#pragma unroll
        for (int r = 0; r < 4; ++r) {
            const int qi = (l >> 4) * 4 + r;
            rL[qblk][r] = 1.0f / (Lb[qblk * 16 + qi] + Lb[(qblk + 2) * 16 + qi]);
        }

    const float g = gamma[0];
#pragma unroll
    for (int qblk = 0; qblk < 2; ++qblk)
#pragma unroll
        for (int eb = 0; eb < 4; ++eb) {
            const int e = w * 64 + eb * 16 + (l & 15);
#pragma unroll
            for (int r = 0; r < 4; ++r) {
                const int n = q0 + qblk * 16 + (l >> 4) * 4 + r;
                const size_t idx = ((size_t)b * C_ + e) * N_ + n;
                out[idx] = g * acc[qblk][eb][r] * rL[qblk][r] + x[idx];
            }
        }
}

extern "C" void kernel_launch(void* const* d_in, const int* in_sizes, int n_in,
                              void* d_out, int out_size, void* d_ws, size_t ws_size,
                              hipStream_t stream) {
    (void)in_sizes; (void)n_in; (void)out_size; (void)ws_size;
    const float* x     = (const float*)d_in[0];
    const float* y     = (const float*)d_in[1];
    const float* Wq    = (const float*)d_in[2];
    const float* bq    = (const float*)d_in[3];
    const float* Wk    = (const float*)d_in[4];
    const float* bk    = (const float*)d_in[5];
    const float* Wv    = (const float*)d_in[6];
    const float* bv    = (const float*)d_in[7];
    const float* gamma = (const float*)d_in[8];
    float* out = (float*)d_out;

    // ws: qf 1MB | kf 1MB | vf 8MB | Wqb/Wkb/Wvb bf16 (160KB)
    unsigned short* qf  = (unsigned short*)d_ws;
    unsigned short* kf  = qf + (size_t)B_ * N_ * CQK_;
    unsigned short* vf  = kf + (size_t)B_ * N_ * CQK_;
    unsigned short* Wqb = vf + (size_t)B_ * N_ * C_;
    unsigned short* Wkb = Wqb + CQK_ * C_;
    unsigned short* Wvb = Wkb + CQK_ * C_;

    // transposed bf16 inputs live in d_out (dead until attn's epilogue): xb 8MB | yb 8MB
    unsigned short* xb = (unsigned short*)d_out;
    unsigned short* yb = xb + (size_t)B_ * N_ * C_;

    transpose_kernel<<<dim3(576), 256, 0, stream>>>(x, y, Wq, Wk, Wv, xb, yb, Wqb, Wkb, Wvb);
    proj_gemm<<<dim3(256), 256, 0, stream>>>(xb, yb, Wqb, Wkb, Wvb, bq, bk, bv, qf, kf, vf);
    attn_kernel<<<dim3(512), 256, 0, stream>>>(qf, kf, vf, x, gamma, out);
}